// Round 5
// baseline (92.225 us; speedup 1.0000x reference)
//
#include <hip/hip_runtime.h>
#include <hip/hip_bf16.h>
#include <math.h>

typedef __attribute__((ext_vector_type(8))) __bf16 bf16x8;
typedef __attribute__((ext_vector_type(4))) __bf16 bf16x4;
typedef __attribute__((ext_vector_type(4))) float f32x4;

#define EE 1024
#define HH 16
#define DD 64
#define BB 8
#define TT 64
#define NSPLIT 8

__device__ __forceinline__ f32x4 mfma16(bf16x8 a, bf16x8 b, f32x4 c) {
    return __builtin_amdgcn_mfma_f32_16x16x32_bf16(a, b, c, 0, 0, 0);
}

// ---- fused QKV projection + RoPE: reads x/W in f32 directly, BM=128 ----
// grid = 192 (XCD-swizzled: 24 blocks/XCD = 6 bn panels x 4 bm), block = 256
__global__ __launch_bounds__(256) void k_qkv(const float* __restrict__ x, const float* __restrict__ Wq,
                                             const float* __restrict__ Wk, const float* __restrict__ Wv,
                                             const int* __restrict__ sp_ptr,
                                             __bf16* __restrict__ qws, __bf16* __restrict__ knew,
                                             __bf16* __restrict__ vnew) {
    __shared__ __bf16 a_lds[128][72];   // x tile, row-major [m][k]
    __shared__ __bf16 b_lds[64][72];    // W tile transposed [n][k]
    __shared__ float cs_l[32], sn_l[32];
    int xcd = blockIdx.x & 7, idx = blockIdx.x >> 3;
    int bn = xcd * 6 + idx % 6;          // W panel stays in this XCD's L2
    int bm = idx / 6;
    int wsel = bn >> 4;                  // 0=q, 1=k, 2=v
    int n0 = (bn & 15) * 64;
    int m0 = bm * 128;
    const float* W = (wsel == 0) ? Wq : (wsel == 1) ? Wk : Wv;
    int tid = threadIdx.x;
    int wv = tid >> 6, lane = tid & 63;
    int l16 = lane & 15, lhi = lane >> 4;
    int g = tid >> 4, m4 = (tid & 15) * 4;   // staging coords

    f32x4 acc[2][4];
#pragma unroll
    for (int im = 0; im < 2; ++im)
#pragma unroll
        for (int f = 0; f < 4; ++f) acc[im][f] = (f32x4){0.f, 0.f, 0.f, 0.f};

    // prologue loads for kt=0 (A: 128x64 f32 of x; B: 64x64 f32 of W)
    f32x4 areg[8], breg[4];
#pragma unroll
    for (int p = 0; p < 8; ++p)
        areg[p] = *(const f32x4*)&x[(size_t)(m0 + p * 16 + g) * EE + m4];
#pragma unroll
    for (int i = 0; i < 4; ++i)
        breg[i] = *(const f32x4*)&W[(size_t)(4 * g + i) * EE + n0 + m4];

    // RoPE table for this block's single head (overlaps with loads in flight)
    if (tid < 32) {
        int h = bn & 15;
        int sp = sp_ptr[0];
        float invf = powf(10000.0f, -(float)tid / 32.0f);
        float ang = (float)(sp + h) * invf;
        float s, c;
        sincosf(ang, &s, &c);
        cs_l[tid] = c;
        sn_l[tid] = s;
    }

    for (int kt = 0; kt < 16; ++kt) {
        __syncthreads();
        // A: straight convert (row-major)
#pragma unroll
        for (int p = 0; p < 8; ++p) {
            bf16x4 a4 = { (__bf16)areg[p][0], (__bf16)areg[p][1], (__bf16)areg[p][2], (__bf16)areg[p][3] };
            *(bf16x4*)&a_lds[p * 16 + g][m4] = a4;
        }
        // B: in-register 4x4 transpose -> [n][k]
#pragma unroll
        for (int j = 0; j < 4; ++j) {
            bf16x4 t4 = { (__bf16)breg[0][j], (__bf16)breg[1][j], (__bf16)breg[2][j], (__bf16)breg[3][j] };
            *(bf16x4*)&b_lds[m4 + j][4 * g] = t4;
        }
        if (kt < 15) {
            int ko = (kt + 1) * 64;
#pragma unroll
            for (int p = 0; p < 8; ++p)
                areg[p] = *(const f32x4*)&x[(size_t)(m0 + p * 16 + g) * EE + ko + m4];
#pragma unroll
            for (int i = 0; i < 4; ++i)
                breg[i] = *(const f32x4*)&W[(size_t)(ko + 4 * g + i) * EE + n0 + m4];
        }
        __syncthreads();
        bf16x8 a0[2], a1[2];
#pragma unroll
        for (int im = 0; im < 2; ++im) {
            a0[im] = *(bf16x8*)&a_lds[wv * 32 + im * 16 + l16][lhi * 8];
            a1[im] = *(bf16x8*)&a_lds[wv * 32 + im * 16 + l16][32 + lhi * 8];
        }
#pragma unroll
        for (int f = 0; f < 4; ++f) {
            bf16x8 b0 = *(bf16x8*)&b_lds[f * 16 + l16][lhi * 8];
            bf16x8 b1 = *(bf16x8*)&b_lds[f * 16 + l16][32 + lhi * 8];
#pragma unroll
            for (int im = 0; im < 2; ++im) {
                acc[im][f] = mfma16(a0[im], b0, acc[im][f]);
                acc[im][f] = mfma16(a1[im], b1, acc[im][f]);
            }
        }
    }
    __bf16* dst = (wsel == 0) ? qws : (wsel == 1) ? knew : vnew;
    int h = bn & 15;
#pragma unroll
    for (int im = 0; im < 2; ++im) {
#pragma unroll
        for (int f = 0; f < 4; ++f) {
#pragma unroll
            for (int r = 0; r < 4; ++r) {
                float v = acc[im][f][r];
                int row = m0 + wv * 32 + im * 16 + lhi * 4 + r;
                int d = f * 16 + l16;
                float o = v;
                if (wsel < 2) {
                    float other = __shfl_xor(v, 1);   // partner column (d^1) same row
                    int pp = d >> 1;
                    float c = cs_l[pp], s = sn_l[pp];
                    o = ((d & 1) == 0) ? (v * c - other * s) : (other * s + v * c);
                }
                int b = row >> 6, t = row & 63;
                dst[((size_t)((b * HH + h) * TT + t)) * DD + d] = (__bf16)o;
            }
        }
    }
}

// ---- flash-decoding attention: reg prefetch + in-register V transpose ----
// grid = B*H*NSPLIT (=1024, 4 blocks/CU), block = 256 (4 waves)
__global__ __launch_bounds__(256, 4) void k_attn(const __bf16* __restrict__ qws, const __bf16* __restrict__ knew,
                                                 const __bf16* __restrict__ vnew,
                                                 const float* __restrict__ ck, const float* __restrict__ cv,
                                                 __bf16* __restrict__ Opart, float2* __restrict__ mlpart) {
    __shared__ __bf16 k_lds[64][72];    // [s][d]
    __shared__ __bf16 vT_lds[64][68];   // [d][s]
    __shared__ __bf16 p_lds[64][72];    // [t][s] (wave-local rows)
    int bh = blockIdx.x >> 3, split = blockIdx.x & 7;
    int b = bh >> 4, h = bh & 15;
    int tid = threadIdx.x, wv = tid >> 6, lane = tid & 63;
    int l16 = lane & 15, lhi = lane >> 4;
    int g = tid >> 4, m4 = (tid & 15) * 4;   // staging coords

    bf16x8 qf0, qf1;
    {
        const __bf16* qp = qws + ((size_t)bh * TT + (wv * 16 + l16)) * DD;
        qf0 = *(const bf16x8*)&qp[lhi * 8];
        qf1 = *(const bf16x8*)&qp[32 + lhi * 8];
    }
    f32x4 acc[4];
#pragma unroll
    for (int f = 0; f < 4; ++f) acc[f] = (f32x4){0.f, 0.f, 0.f, 0.f};
    float m[4], l[4];
#pragma unroll
    for (int r = 0; r < 4; ++r) { m[r] = -1e30f; l[r] = 0.f; }

    const float* ckb = ck + (size_t)b * 8192 * EE + h * DD;   // row stride EE floats
    const float* cvb = cv + (size_t)b * 8192 * EE + h * DD;
    int s0 = split * 512;

    auto compute = [&](bool mask) {
        f32x4 sf[4];
#pragma unroll
        for (int f = 0; f < 4; ++f) {
            f32x4 z = (f32x4){0.f, 0.f, 0.f, 0.f};
            bf16x8 b0 = *(bf16x8*)&k_lds[f * 16 + l16][lhi * 8];
            bf16x8 b1 = *(bf16x8*)&k_lds[f * 16 + l16][32 + lhi * 8];
            z = mfma16(qf0, b0, z);
            z = mfma16(qf1, b1, z);
            sf[f] = z;
        }
#pragma unroll
        for (int f = 0; f < 4; ++f) {
#pragma unroll
            for (int r = 0; r < 4; ++r) {
                float sv = sf[f][r] * 0.125f;
                if (mask) {
                    int t_row = wv * 16 + lhi * 4 + r;
                    int s_loc = f * 16 + l16;
                    if (s_loc > t_row) sv = -1e30f;
                }
                sf[f][r] = sv;
            }
        }
        float mt[4];
#pragma unroll
        for (int r = 0; r < 4; ++r)
            mt[r] = fmaxf(fmaxf(sf[0][r], sf[1][r]), fmaxf(sf[2][r], sf[3][r]));
#pragma unroll
        for (int off = 1; off < 16; off <<= 1) {
#pragma unroll
            for (int r = 0; r < 4; ++r) mt[r] = fmaxf(mt[r], __shfl_xor(mt[r], off));
        }
        float fac[4];
#pragma unroll
        for (int r = 0; r < 4; ++r) {
            float mn = fmaxf(m[r], mt[r]);
            fac[r] = __expf(m[r] - mn);
            m[r] = mn;
        }
        float ladd[4] = {0.f, 0.f, 0.f, 0.f};
#pragma unroll
        for (int f = 0; f < 4; ++f) {
#pragma unroll
            for (int r = 0; r < 4; ++r) {
                float pv = __expf(sf[f][r] - m[r]);
                sf[f][r] = pv;
                ladd[r] += pv;
            }
        }
#pragma unroll
        for (int off = 1; off < 16; off <<= 1) {
#pragma unroll
            for (int r = 0; r < 4; ++r) ladd[r] += __shfl_xor(ladd[r], off);
        }
#pragma unroll
        for (int r = 0; r < 4; ++r) l[r] = l[r] * fac[r] + ladd[r];
#pragma unroll
        for (int f = 0; f < 4; ++f)
#pragma unroll
            for (int r = 0; r < 4; ++r) acc[f][r] *= fac[r];
#pragma unroll
        for (int f = 0; f < 4; ++f)
#pragma unroll
            for (int r = 0; r < 4; ++r)
                p_lds[wv * 16 + lhi * 4 + r][f * 16 + l16] = (__bf16)sf[f][r];
        bf16x8 pa0 = *(bf16x8*)&p_lds[wv * 16 + l16][lhi * 8];
        bf16x8 pa1 = *(bf16x8*)&p_lds[wv * 16 + l16][32 + lhi * 8];
#pragma unroll
        for (int f = 0; f < 4; ++f) {
            bf16x8 v0 = *(bf16x8*)&vT_lds[f * 16 + l16][lhi * 8];
            bf16x8 v1 = *(bf16x8*)&vT_lds[f * 16 + l16][32 + lhi * 8];
            acc[f] = mfma16(pa0, v0, acc[f]);
            acc[f] = mfma16(pa1, v1, acc[f]);
        }
    };

    // prefetch tile 0: K rows g+16p, V rows 4g+i (consecutive, for in-reg transpose)
    f32x4 kreg[4], vreg[4];
#pragma unroll
    for (int p = 0; p < 4; ++p)
        kreg[p] = *(const f32x4*)&ckb[(size_t)(s0 + p * 16 + g) * EE + m4];
#pragma unroll
    for (int i = 0; i < 4; ++i)
        vreg[i] = *(const f32x4*)&cvb[(size_t)(s0 + 4 * g + i) * EE + m4];

    for (int it = 0; it < 8; ++it) {
#pragma unroll
        for (int p = 0; p < 4; ++p) {
            bf16x4 k4 = { (__bf16)kreg[p][0], (__bf16)kreg[p][1], (__bf16)kreg[p][2], (__bf16)kreg[p][3] };
            *(bf16x4*)&k_lds[p * 16 + g][m4] = k4;
        }
#pragma unroll
        for (int j = 0; j < 4; ++j) {
            bf16x4 tv = { (__bf16)vreg[0][j], (__bf16)vreg[1][j], (__bf16)vreg[2][j], (__bf16)vreg[3][j] };
            *(bf16x4*)&vT_lds[m4 + j][4 * g] = tv;
        }
        if (it < 7) {
            int sb = s0 + (it + 1) * 64;
#pragma unroll
            for (int p = 0; p < 4; ++p)
                kreg[p] = *(const f32x4*)&ckb[(size_t)(sb + p * 16 + g) * EE + m4];
#pragma unroll
            for (int i = 0; i < 4; ++i)
                vreg[i] = *(const f32x4*)&cvb[(size_t)(sb + 4 * g + i) * EE + m4];
        }
        __syncthreads();
        compute(false);
        __syncthreads();
    }

    if (split == 7) {
#pragma unroll
        for (int p = 0; p < 2; ++p) {
            int idx = p * 256 + tid;
            int r = idx >> 3, c8 = (idx & 7) * 8;
            *(bf16x8*)&k_lds[r][c8] = *(const bf16x8*)&knew[((size_t)bh * TT + r) * DD + c8];
            bf16x8 vf = *(const bf16x8*)&vnew[((size_t)bh * TT + r) * DD + c8];
#pragma unroll
            for (int j = 0; j < 8; ++j) vT_lds[c8 + j][r] = vf[j];
        }
        __syncthreads();
        compute(true);
    }

    // store partials (bf16 O, float2 m/l)
#pragma unroll
    for (int f = 0; f < 4; ++f)
#pragma unroll
        for (int r = 0; r < 4; ++r) {
            int t = wv * 16 + lhi * 4 + r;
            int d = f * 16 + l16;
            Opart[(((size_t)split * 128 + bh) * TT + t) * DD + d] = (__bf16)acc[f][r];
        }
    if (l16 == 0) {
#pragma unroll
        for (int r = 0; r < 4; ++r) {
            int t = wv * 16 + lhi * 4 + r;
            mlpart[((size_t)split * 128 + bh) * TT + t] = make_float2(m[r], l[r]);
        }
    }
}

// ---- combine split partials -> ctx bf16 (row-major tokens x E) ----
__global__ __launch_bounds__(256) void k_combine(const __bf16* __restrict__ Opart, const float2* __restrict__ mlpart,
                                                 __bf16* __restrict__ ctxb) {
    int idx = blockIdx.x * 256 + threadIdx.x;   // B*H*T*D = 524288
    int d = idx & 63, t = (idx >> 6) & 63, bh = idx >> 12;
    float ms[NSPLIT], ls[NSPLIT];
    float mg = -1e30f;
#pragma unroll
    for (int s = 0; s < NSPLIT; ++s) {
        float2 ml = mlpart[((size_t)s * 128 + bh) * TT + t];
        ms[s] = ml.x; ls[s] = ml.y;
        mg = fmaxf(mg, ms[s]);
    }
    float den = 0.f, num = 0.f;
#pragma unroll
    for (int s = 0; s < NSPLIT; ++s) {
        float w = __expf(ms[s] - mg);
        den += ls[s] * w;
        num += (float)Opart[(((size_t)s * 128 + bh) * TT + t) * DD + d] * w;
    }
    float ctx = num / den;
    int b = bh >> 4, hh = bh & 15;
    ctxb[(size_t)(b * TT + t) * EE + hh * DD + d] = (__bf16)ctx;
}

// ---- output projection: out = ctx @ Wo, Wo transposed on the fly, BM=128 ----
// grid = 64 (XCD-swizzled), block = 256
__global__ __launch_bounds__(256) void k_oproj(const __bf16* __restrict__ ctxb, const float* __restrict__ Wo,
                                               float* __restrict__ out) {
    __shared__ __bf16 a_lds[128][72];
    __shared__ __bf16 b_lds[64][72];
    int xcd = blockIdx.x & 7, idx = blockIdx.x >> 3;
    int bn = xcd * 2 + (idx & 1);
    int bm = idx >> 1;
    int n0 = bn * 64, m0 = bm * 128;
    int tid = threadIdx.x;
    int wv = tid >> 6, lane = tid & 63;
    int l16 = lane & 15, lhi = lane >> 4;
    int g = tid >> 4, m4 = (tid & 15) * 4;   // B staging
    int q8 = tid >> 3, c8 = (tid & 7) * 8;   // A staging
    f32x4 acc[2][4];
#pragma unroll
    for (int im = 0; im < 2; ++im)
#pragma unroll
        for (int f = 0; f < 4; ++f) acc[im][f] = (f32x4){0.f, 0.f, 0.f, 0.f};

    bf16x8 areg[4];
    f32x4 breg[4];
#pragma unroll
    for (int p = 0; p < 4; ++p)
        areg[p] = *(const bf16x8*)&ctxb[(size_t)(m0 + p * 32 + q8) * EE + c8];
#pragma unroll
    for (int i = 0; i < 4; ++i)
        breg[i] = *(const f32x4*)&Wo[(size_t)(4 * g + i) * EE + n0 + m4];

    for (int kt = 0; kt < 16; ++kt) {
        __syncthreads();
#pragma unroll
        for (int p = 0; p < 4; ++p)
            *(bf16x8*)&a_lds[p * 32 + q8][c8] = areg[p];
#pragma unroll
        for (int j = 0; j < 4; ++j) {
            bf16x4 t4 = { (__bf16)breg[0][j], (__bf16)breg[1][j], (__bf16)breg[2][j], (__bf16)breg[3][j] };
            *(bf16x4*)&b_lds[m4 + j][4 * g] = t4;
        }
        if (kt < 15) {
            int ko = (kt + 1) * 64;
#pragma unroll
            for (int p = 0; p < 4; ++p)
                areg[p] = *(const bf16x8*)&ctxb[(size_t)(m0 + p * 32 + q8) * EE + ko + c8];
#pragma unroll
            for (int i = 0; i < 4; ++i)
                breg[i] = *(const f32x4*)&Wo[(size_t)(ko + 4 * g + i) * EE + n0 + m4];
        }
        __syncthreads();
        bf16x8 a0[2], a1[2];
#pragma unroll
        for (int im = 0; im < 2; ++im) {
            a0[im] = *(bf16x8*)&a_lds[wv * 32 + im * 16 + l16][lhi * 8];
            a1[im] = *(bf16x8*)&a_lds[wv * 32 + im * 16 + l16][32 + lhi * 8];
        }
#pragma unroll
        for (int f = 0; f < 4; ++f) {
            bf16x8 b0 = *(bf16x8*)&b_lds[f * 16 + l16][lhi * 8];
            bf16x8 b1 = *(bf16x8*)&b_lds[f * 16 + l16][32 + lhi * 8];
#pragma unroll
            for (int im = 0; im < 2; ++im) {
                acc[im][f] = mfma16(a0[im], b0, acc[im][f]);
                acc[im][f] = mfma16(a1[im], b1, acc[im][f]);
            }
        }
    }
#pragma unroll
    for (int im = 0; im < 2; ++im)
#pragma unroll
        for (int f = 0; f < 4; ++f)
#pragma unroll
            for (int r = 0; r < 4; ++r) {
                int row = m0 + wv * 32 + im * 16 + lhi * 4 + r;
                out[(size_t)row * EE + n0 + f * 16 + l16] = acc[im][f][r];
            }
}

extern "C" void kernel_launch(void* const* d_in, const int* in_sizes, int n_in,
                              void* d_out, int out_size, void* d_ws, size_t ws_size,
                              hipStream_t stream) {
    const float* x  = (const float*)d_in[0];
    const float* ck = (const float*)d_in[1];
    const float* cv = (const float*)d_in[2];
    const float* Wq = (const float*)d_in[3];
    const float* Wk = (const float*)d_in[4];
    const float* Wv = (const float*)d_in[5];
    const float* Wo = (const float*)d_in[6];
    const int* sp   = (const int*)d_in[7];
    float* out = (float*)d_out;

    char* p = (char*)d_ws;
    __bf16* qws = (__bf16*)p;           p += (size_t)524288 * 2;
    __bf16* knew = (__bf16*)p;          p += (size_t)524288 * 2;
    __bf16* vnew = (__bf16*)p;          p += (size_t)524288 * 2;
    __bf16* Opart = (__bf16*)p;         p += (size_t)NSPLIT * 128 * 64 * 64 * 2;
    float2* mlpart = (float2*)p;        p += (size_t)NSPLIT * 8192 * 8;
    __bf16* ctxb = (__bf16*)p;          p += (size_t)524288 * 2;

    k_qkv<<<192, 256, 0, stream>>>(x, Wq, Wk, Wv, sp, qws, knew, vnew);
    k_attn<<<BB * HH * NSPLIT, 256, 0, stream>>>(qws, knew, vnew, ck, cv, Opart, mlpart);
    k_combine<<<2048, 256, 0, stream>>>(Opart, mlpart, ctxb);
    k_oproj<<<64, 256, 0, stream>>>(ctxb, Wo, out);
}

// Round 6
// 88.452 us; speedup vs baseline: 1.0427x; 1.0427x over previous
//
#include <hip/hip_runtime.h>
#include <hip/hip_bf16.h>
#include <math.h>

typedef __attribute__((ext_vector_type(8))) __bf16 bf16x8;
typedef __attribute__((ext_vector_type(4))) __bf16 bf16x4;
typedef __attribute__((ext_vector_type(4))) float f32x4;

#define EE 1024
#define HH 16
#define DD 64
#define BB 8
#define TT 64
#define NSPLIT 8

__device__ __forceinline__ f32x4 mfma16(bf16x8 a, bf16x8 b, f32x4 c) {
    return __builtin_amdgcn_mfma_f32_16x16x32_bf16(a, b, c, 0, 0, 0);
}

// ---- fused QKV projection + RoPE: f32-direct reads, BM=64, grid=384 ----
// XCD-swizzled: each XCD owns 6 bn panels x 8 bm -> W panel stays in its L2
__global__ __launch_bounds__(256) void k_qkv(const float* __restrict__ x, const float* __restrict__ Wq,
                                             const float* __restrict__ Wk, const float* __restrict__ Wv,
                                             const int* __restrict__ sp_ptr,
                                             __bf16* __restrict__ qws, __bf16* __restrict__ knew,
                                             __bf16* __restrict__ vnew) {
    __shared__ __bf16 a_lds[64][72];    // x tile [m][k], wide row writes
    __shared__ __bf16 b_lds[64][68];    // W^T tile [n][k], 4x4 in-reg transpose writes (4-way)
    __shared__ float cs_l[32], sn_l[32];
    int xcd = blockIdx.x & 7, idx = blockIdx.x >> 3;   // idx 0..47
    int bn = xcd * 6 + idx % 6;          // 0..47
    int bm = idx / 6;                    // 0..7
    int wsel = bn >> 4;                  // 0=q, 1=k, 2=v
    int n0 = (bn & 15) * 64;
    int m0 = bm * 64;
    const float* W = (wsel == 0) ? Wq : (wsel == 1) ? Wk : Wv;
    int tid = threadIdx.x;
    int wv = tid >> 6, lane = tid & 63;
    int l16 = lane & 15, lhi = lane >> 4;
    int g = tid >> 4, m4 = (tid & 15) * 4;   // staging coords

    f32x4 acc[4];
#pragma unroll
    for (int f = 0; f < 4; ++f) acc[f] = (f32x4){0.f, 0.f, 0.f, 0.f};

    // prologue loads for kt=0
    f32x4 areg[4], breg[4];
#pragma unroll
    for (int p = 0; p < 4; ++p)
        areg[p] = *(const f32x4*)&x[(size_t)(m0 + p * 16 + g) * EE + m4];
#pragma unroll
    for (int i = 0; i < 4; ++i)
        breg[i] = *(const f32x4*)&W[(size_t)(4 * g + i) * EE + n0 + m4];

    // RoPE table for this block's single head (overlaps with loads in flight)
    if (tid < 32) {
        int h = bn & 15;
        int sp = sp_ptr[0];
        float invf = powf(10000.0f, -(float)tid / 32.0f);
        float ang = (float)(sp + h) * invf;
        float s, c;
        sincosf(ang, &s, &c);
        cs_l[tid] = c;
        sn_l[tid] = s;
    }

    for (int kt = 0; kt < 16; ++kt) {
        __syncthreads();
#pragma unroll
        for (int p = 0; p < 4; ++p) {
            bf16x4 a4 = { (__bf16)areg[p][0], (__bf16)areg[p][1], (__bf16)areg[p][2], (__bf16)areg[p][3] };
            *(bf16x4*)&a_lds[p * 16 + g][m4] = a4;
        }
#pragma unroll
        for (int j = 0; j < 4; ++j) {
            bf16x4 t4 = { (__bf16)breg[0][j], (__bf16)breg[1][j], (__bf16)breg[2][j], (__bf16)breg[3][j] };
            *(bf16x4*)&b_lds[m4 + j][4 * g] = t4;
        }
        if (kt < 15) {
            int ko = (kt + 1) * 64;
#pragma unroll
            for (int p = 0; p < 4; ++p)
                areg[p] = *(const f32x4*)&x[(size_t)(m0 + p * 16 + g) * EE + ko + m4];
#pragma unroll
            for (int i = 0; i < 4; ++i)
                breg[i] = *(const f32x4*)&W[(size_t)(ko + 4 * g + i) * EE + n0 + m4];
        }
        __syncthreads();
        bf16x8 a0 = *(bf16x8*)&a_lds[wv * 16 + l16][lhi * 8];
        bf16x8 a1 = *(bf16x8*)&a_lds[wv * 16 + l16][32 + lhi * 8];
#pragma unroll
        for (int f = 0; f < 4; ++f) {
            bf16x8 b0 = *(bf16x8*)&b_lds[f * 16 + l16][lhi * 8];
            bf16x8 b1 = *(bf16x8*)&b_lds[f * 16 + l16][32 + lhi * 8];
            acc[f] = mfma16(a0, b0, acc[f]);
            acc[f] = mfma16(a1, b1, acc[f]);
        }
    }
    __bf16* dst = (wsel == 0) ? qws : (wsel == 1) ? knew : vnew;
    int h = bn & 15;
#pragma unroll
    for (int f = 0; f < 4; ++f) {
#pragma unroll
        for (int r = 0; r < 4; ++r) {
            float v = acc[f][r];
            int row = m0 + wv * 16 + lhi * 4 + r;
            int d = f * 16 + l16;
            float o = v;
            if (wsel < 2) {
                float other = __shfl_xor(v, 1);   // partner column (d^1) same row
                int pp = d >> 1;
                float c = cs_l[pp], s = sn_l[pp];
                o = ((d & 1) == 0) ? (v * c - other * s) : (other * s + v * c);
            }
            int b = row >> 6, t = row & 63;
            dst[((size_t)((b * HH + h) * TT + t)) * DD + d] = (__bf16)o;
        }
    }
}

// ---- flash-decoding attention: reg prefetch + in-register V transpose ----
// grid = B*H*NSPLIT (=1024, 4 blocks/CU), block = 256 (4 waves)
__global__ __launch_bounds__(256, 4) void k_attn(const __bf16* __restrict__ qws, const __bf16* __restrict__ knew,
                                                 const __bf16* __restrict__ vnew,
                                                 const float* __restrict__ ck, const float* __restrict__ cv,
                                                 __bf16* __restrict__ Opart, float2* __restrict__ mlpart) {
    __shared__ __bf16 k_lds[64][72];    // [s][d]
    __shared__ __bf16 vT_lds[64][68];   // [d][s]
    __shared__ __bf16 p_lds[64][72];    // [t][s] (wave-local rows)
    int bh = blockIdx.x >> 3, split = blockIdx.x & 7;
    int b = bh >> 4, h = bh & 15;
    int tid = threadIdx.x, wv = tid >> 6, lane = tid & 63;
    int l16 = lane & 15, lhi = lane >> 4;
    int g = tid >> 4, m4 = (tid & 15) * 4;   // staging coords

    bf16x8 qf0, qf1;
    {
        const __bf16* qp = qws + ((size_t)bh * TT + (wv * 16 + l16)) * DD;
        qf0 = *(const bf16x8*)&qp[lhi * 8];
        qf1 = *(const bf16x8*)&qp[32 + lhi * 8];
    }
    f32x4 acc[4];
#pragma unroll
    for (int f = 0; f < 4; ++f) acc[f] = (f32x4){0.f, 0.f, 0.f, 0.f};
    float m[4], l[4];
#pragma unroll
    for (int r = 0; r < 4; ++r) { m[r] = -1e30f; l[r] = 0.f; }

    const float* ckb = ck + (size_t)b * 8192 * EE + h * DD;   // row stride EE floats
    const float* cvb = cv + (size_t)b * 8192 * EE + h * DD;
    int s0 = split * 512;

    auto compute = [&](bool mask) {
        f32x4 sf[4];
#pragma unroll
        for (int f = 0; f < 4; ++f) {
            f32x4 z = (f32x4){0.f, 0.f, 0.f, 0.f};
            bf16x8 b0 = *(bf16x8*)&k_lds[f * 16 + l16][lhi * 8];
            bf16x8 b1 = *(bf16x8*)&k_lds[f * 16 + l16][32 + lhi * 8];
            z = mfma16(qf0, b0, z);
            z = mfma16(qf1, b1, z);
            sf[f] = z;
        }
#pragma unroll
        for (int f = 0; f < 4; ++f) {
#pragma unroll
            for (int r = 0; r < 4; ++r) {
                float sv = sf[f][r] * 0.125f;
                if (mask) {
                    int t_row = wv * 16 + lhi * 4 + r;
                    int s_loc = f * 16 + l16;
                    if (s_loc > t_row) sv = -1e30f;
                }
                sf[f][r] = sv;
            }
        }
        float mt[4];
#pragma unroll
        for (int r = 0; r < 4; ++r)
            mt[r] = fmaxf(fmaxf(sf[0][r], sf[1][r]), fmaxf(sf[2][r], sf[3][r]));
#pragma unroll
        for (int off = 1; off < 16; off <<= 1) {
#pragma unroll
            for (int r = 0; r < 4; ++r) mt[r] = fmaxf(mt[r], __shfl_xor(mt[r], off));
        }
        float fac[4];
#pragma unroll
        for (int r = 0; r < 4; ++r) {
            float mn = fmaxf(m[r], mt[r]);
            fac[r] = __expf(m[r] - mn);
            m[r] = mn;
        }
        float ladd[4] = {0.f, 0.f, 0.f, 0.f};
#pragma unroll
        for (int f = 0; f < 4; ++f) {
#pragma unroll
            for (int r = 0; r < 4; ++r) {
                float pv = __expf(sf[f][r] - m[r]);
                sf[f][r] = pv;
                ladd[r] += pv;
            }
        }
#pragma unroll
        for (int off = 1; off < 16; off <<= 1) {
#pragma unroll
            for (int r = 0; r < 4; ++r) ladd[r] += __shfl_xor(ladd[r], off);
        }
#pragma unroll
        for (int r = 0; r < 4; ++r) l[r] = l[r] * fac[r] + ladd[r];
#pragma unroll
        for (int f = 0; f < 4; ++f)
#pragma unroll
            for (int r = 0; r < 4; ++r) acc[f][r] *= fac[r];
#pragma unroll
        for (int f = 0; f < 4; ++f)
#pragma unroll
            for (int r = 0; r < 4; ++r)
                p_lds[wv * 16 + lhi * 4 + r][f * 16 + l16] = (__bf16)sf[f][r];
        bf16x8 pa0 = *(bf16x8*)&p_lds[wv * 16 + l16][lhi * 8];
        bf16x8 pa1 = *(bf16x8*)&p_lds[wv * 16 + l16][32 + lhi * 8];
#pragma unroll
        for (int f = 0; f < 4; ++f) {
            bf16x8 v0 = *(bf16x8*)&vT_lds[f * 16 + l16][lhi * 8];
            bf16x8 v1 = *(bf16x8*)&vT_lds[f * 16 + l16][32 + lhi * 8];
            acc[f] = mfma16(pa0, v0, acc[f]);
            acc[f] = mfma16(pa1, v1, acc[f]);
        }
    };

    // prefetch tile 0: K rows g+16p, V rows 4g+i (consecutive, for in-reg transpose)
    f32x4 kreg[4], vreg[4];
#pragma unroll
    for (int p = 0; p < 4; ++p)
        kreg[p] = *(const f32x4*)&ckb[(size_t)(s0 + p * 16 + g) * EE + m4];
#pragma unroll
    for (int i = 0; i < 4; ++i)
        vreg[i] = *(const f32x4*)&cvb[(size_t)(s0 + 4 * g + i) * EE + m4];

    for (int it = 0; it < 8; ++it) {
#pragma unroll
        for (int p = 0; p < 4; ++p) {
            bf16x4 k4 = { (__bf16)kreg[p][0], (__bf16)kreg[p][1], (__bf16)kreg[p][2], (__bf16)kreg[p][3] };
            *(bf16x4*)&k_lds[p * 16 + g][m4] = k4;
        }
#pragma unroll
        for (int j = 0; j < 4; ++j) {
            bf16x4 tv = { (__bf16)vreg[0][j], (__bf16)vreg[1][j], (__bf16)vreg[2][j], (__bf16)vreg[3][j] };
            *(bf16x4*)&vT_lds[m4 + j][4 * g] = tv;
        }
        if (it < 7) {
            int sb = s0 + (it + 1) * 64;
#pragma unroll
            for (int p = 0; p < 4; ++p)
                kreg[p] = *(const f32x4*)&ckb[(size_t)(sb + p * 16 + g) * EE + m4];
#pragma unroll
            for (int i = 0; i < 4; ++i)
                vreg[i] = *(const f32x4*)&cvb[(size_t)(sb + 4 * g + i) * EE + m4];
        }
        __syncthreads();
        compute(false);
        __syncthreads();
    }

    if (split == 7) {
#pragma unroll
        for (int p = 0; p < 2; ++p) {
            int idx = p * 256 + tid;
            int r = idx >> 3, c8 = (idx & 7) * 8;
            *(bf16x8*)&k_lds[r][c8] = *(const bf16x8*)&knew[((size_t)bh * TT + r) * DD + c8];
            bf16x8 vf = *(const bf16x8*)&vnew[((size_t)bh * TT + r) * DD + c8];
#pragma unroll
            for (int j = 0; j < 8; ++j) vT_lds[c8 + j][r] = vf[j];
        }
        __syncthreads();
        compute(true);
    }

    // store partials (bf16 O, float2 m/l)
#pragma unroll
    for (int f = 0; f < 4; ++f)
#pragma unroll
        for (int r = 0; r < 4; ++r) {
            int t = wv * 16 + lhi * 4 + r;
            int d = f * 16 + l16;
            Opart[(((size_t)split * 128 + bh) * TT + t) * DD + d] = (__bf16)acc[f][r];
        }
    if (l16 == 0) {
#pragma unroll
        for (int r = 0; r < 4; ++r) {
            int t = wv * 16 + lhi * 4 + r;
            mlpart[((size_t)split * 128 + bh) * TT + t] = make_float2(m[r], l[r]);
        }
    }
}

// ---- combine split partials -> ctx bf16 (row-major tokens x E) ----
__global__ __launch_bounds__(256) void k_combine(const __bf16* __restrict__ Opart, const float2* __restrict__ mlpart,
                                                 __bf16* __restrict__ ctxb) {
    int idx = blockIdx.x * 256 + threadIdx.x;   // B*H*T*D = 524288
    int d = idx & 63, t = (idx >> 6) & 63, bh = idx >> 12;
    float ms[NSPLIT], ls[NSPLIT];
    float mg = -1e30f;
#pragma unroll
    for (int s = 0; s < NSPLIT; ++s) {
        float2 ml = mlpart[((size_t)s * 128 + bh) * TT + t];
        ms[s] = ml.x; ls[s] = ml.y;
        mg = fmaxf(mg, ms[s]);
    }
    float den = 0.f, num = 0.f;
#pragma unroll
    for (int s = 0; s < NSPLIT; ++s) {
        float w = __expf(ms[s] - mg);
        den += ls[s] * w;
        num += (float)Opart[(((size_t)s * 128 + bh) * TT + t) * DD + d] * w;
    }
    float ctx = num / den;
    int b = bh >> 4, hh = bh & 15;
    ctxb[(size_t)(b * TT + t) * EE + hh * DD + d] = (__bf16)ctx;
}

// ---- output projection: out = ctx @ Wo, f32-direct Wo, BM=64, grid=128 ----
__global__ __launch_bounds__(256) void k_oproj(const __bf16* __restrict__ ctxb, const float* __restrict__ Wo,
                                               float* __restrict__ out) {
    __shared__ __bf16 a_lds[64][72];
    __shared__ __bf16 b_lds[64][68];
    int xcd = blockIdx.x & 7, idx = blockIdx.x >> 3;   // idx 0..15
    int bn = xcd * 2 + (idx & 1);
    int bm = idx >> 1;                                  // 0..7
    int n0 = bn * 64, m0 = bm * 64;
    int tid = threadIdx.x;
    int wv = tid >> 6, lane = tid & 63;
    int l16 = lane & 15, lhi = lane >> 4;
    int g = tid >> 4, m4 = (tid & 15) * 4;   // B staging
    int r0 = tid >> 3, c8 = (tid & 7) * 8;   // A staging
    f32x4 acc[4];
#pragma unroll
    for (int f = 0; f < 4; ++f) acc[f] = (f32x4){0.f, 0.f, 0.f, 0.f};

    bf16x8 ar0 = *(const bf16x8*)&ctxb[(size_t)(m0 + r0) * EE + c8];
    bf16x8 ar1 = *(const bf16x8*)&ctxb[(size_t)(m0 + 32 + r0) * EE + c8];
    f32x4 breg[4];
#pragma unroll
    for (int i = 0; i < 4; ++i)
        breg[i] = *(const f32x4*)&Wo[(size_t)(4 * g + i) * EE + n0 + m4];

    for (int kt = 0; kt < 16; ++kt) {
        __syncthreads();
        *(bf16x8*)&a_lds[r0][c8] = ar0;
        *(bf16x8*)&a_lds[32 + r0][c8] = ar1;
#pragma unroll
        for (int j = 0; j < 4; ++j) {
            bf16x4 t4 = { (__bf16)breg[0][j], (__bf16)breg[1][j], (__bf16)breg[2][j], (__bf16)breg[3][j] };
            *(bf16x4*)&b_lds[m4 + j][4 * g] = t4;
        }
        if (kt < 15) {
            int ko = (kt + 1) * 64;
            ar0 = *(const bf16x8*)&ctxb[(size_t)(m0 + r0) * EE + ko + c8];
            ar1 = *(const bf16x8*)&ctxb[(size_t)(m0 + 32 + r0) * EE + ko + c8];
#pragma unroll
            for (int i = 0; i < 4; ++i)
                breg[i] = *(const f32x4*)&Wo[(size_t)(ko + 4 * g + i) * EE + n0 + m4];
        }
        __syncthreads();
        bf16x8 a0 = *(bf16x8*)&a_lds[wv * 16 + l16][lhi * 8];
        bf16x8 a1 = *(bf16x8*)&a_lds[wv * 16 + l16][32 + lhi * 8];
#pragma unroll
        for (int f = 0; f < 4; ++f) {
            bf16x8 b0 = *(bf16x8*)&b_lds[f * 16 + l16][lhi * 8];
            bf16x8 b1 = *(bf16x8*)&b_lds[f * 16 + l16][32 + lhi * 8];
            acc[f] = mfma16(a0, b0, acc[f]);
            acc[f] = mfma16(a1, b1, acc[f]);
        }
    }
#pragma unroll
    for (int f = 0; f < 4; ++f)
#pragma unroll
        for (int r = 0; r < 4; ++r) {
            int row = m0 + wv * 16 + lhi * 4 + r;
            out[(size_t)row * EE + n0 + f * 16 + l16] = acc[f][r];
        }
}

extern "C" void kernel_launch(void* const* d_in, const int* in_sizes, int n_in,
                              void* d_out, int out_size, void* d_ws, size_t ws_size,
                              hipStream_t stream) {
    const float* x  = (const float*)d_in[0];
    const float* ck = (const float*)d_in[1];
    const float* cv = (const float*)d_in[2];
    const float* Wq = (const float*)d_in[3];
    const float* Wk = (const float*)d_in[4];
    const float* Wv = (const float*)d_in[5];
    const float* Wo = (const float*)d_in[6];
    const int* sp   = (const int*)d_in[7];
    float* out = (float*)d_out;

    char* p = (char*)d_ws;
    __bf16* qws = (__bf16*)p;           p += (size_t)524288 * 2;
    __bf16* knew = (__bf16*)p;          p += (size_t)524288 * 2;
    __bf16* vnew = (__bf16*)p;          p += (size_t)524288 * 2;
    __bf16* Opart = (__bf16*)p;         p += (size_t)NSPLIT * 128 * 64 * 64 * 2;
    float2* mlpart = (float2*)p;        p += (size_t)NSPLIT * 8192 * 8;
    __bf16* ctxb = (__bf16*)p;          p += (size_t)524288 * 2;

    k_qkv<<<384, 256, 0, stream>>>(x, Wq, Wk, Wv, sp, qws, knew, vnew);
    k_attn<<<BB * HH * NSPLIT, 256, 0, stream>>>(qws, knew, vnew, ck, cv, Opart, mlpart);
    k_combine<<<2048, 256, 0, stream>>>(Opart, mlpart, ctxb);
    k_oproj<<<128, 256, 0, stream>>>(ctxb, Wo, out);
}